// Round 18
// baseline (57.631 us; speedup 1.0000x reference)
//
#include <hip/hip_runtime.h>
#include <hip/hip_bf16.h>
#include <math.h>

// B=64, C=271, S=512, O=512, K=32.
// out[b,p,q] = sum_c pw[p,c]*y[b,c,q] + pb[p],  y[b,c,q] = sum_s x[b,c,s]*att[s,q]
// att = softmax_o( GT[128,o] . u[c,128] )  (separable fourier reduction)
// R16: both GEMMs at pipeline depth 4 (5 LDS buffers, 3 tiles outstanding,
// counted vmcnt 9/6 steady-state). 80KB pools -> 2 blocks/CU.

typedef short s16x8 __attribute__((ext_vector_type(8)));
typedef short s16x4 __attribute__((ext_vector_type(4)));
typedef float f32x4 __attribute__((ext_vector_type(4)));

#define GLOBAL_AS __attribute__((address_space(1)))
#define LDS_AS    __attribute__((address_space(3)))

__device__ __forceinline__ short f2bf(float f) {
    __hip_bfloat16 h = __float2bfloat16(f);
    return *reinterpret_cast<short*>(&h);
}

#define Cdim 271
#define CpK  288
#define Sdim 512
#define Odim 512
#define MF   17344
#define MFp  17408

// ---------------- gemm7: 128x128, 8 waves, 5 bufs depth-4, f32 A ----------
__global__ __launch_bounds__(512, 4) void gemm7(
    const float* __restrict__ x,
    const short* __restrict__ BT,
    short* __restrict__ yT)
{
    const int m0 = blockIdx.x * 128;     // row tile (x rows)
    const int n0 = blockIdx.y * 128;     // q tile
    // A bufs 5 x 4096 shorts @0; B bufs 5 x 4096 @20480. 80KB.
    // Epilogue reuses pool[0..16896) as T[128][132].
    __shared__ short pool[40960];

    const int t = threadIdx.x;
    const int lane = t & 63;
    const int wid = t >> 6;
    const int wr = wid >> 2;
    const int wc = wid & 3;
    const int lr = lane & 15, lkq = lane >> 4;

    f32x4 acc[4][2];
    #pragma unroll
    for (int i = 0; i < 4; ++i)
        #pragma unroll
        for (int j = 0; j < 2; ++j)
            acc[i][j] = (f32x4){0.f, 0.f, 0.f, 0.f};

    const int srowB = wid * 16 + (lane >> 2);
    const int skk   = (((lane & 3) ^ ((lane >> 3) & 3)) * 8);
    const short* pB = BT + (long)(n0 + srowB) * Sdim + skk;
    const int ldsOff = wid * 512;

    const int arow = t >> 2;
    const int aslot = t & 3;
    const int afc = (aslot ^ ((arow >> 1) & 3)) * 8;
    const int agrow = (m0 + arow < MF) ? (m0 + arow) : (MF - 1);
    const float* pA_f32 = x + (long)agrow * Sdim + afc;
    const int aWr = arow * 32 + aslot * 8;

    const int kxs = ((lkq ^ ((lr >> 1) & 3)) << 3);
    const int aBase = (wr * 64 + lr) * 32 + kxs;
    const int bBase = (wc * 32 + lr) * 32 + kxs;

    auto stageB = [&](int buf, int kt) {
        __builtin_amdgcn_global_load_lds((const GLOBAL_AS void*)(pB + kt * 32),
            (LDS_AS void*)&pool[20480 + buf * 4096 + ldsOff], 16, 0, 0);
    };
    auto compute = [&](int buf) {
        s16x8 af[4], bfv[2];
        #pragma unroll
        for (int m = 0; m < 4; ++m)
            af[m] = *(const s16x8*)&pool[buf * 4096 + aBase + m * 512];
        #pragma unroll
        for (int n = 0; n < 2; ++n)
            bfv[n] = *(const s16x8*)&pool[20480 + buf * 4096 + bBase + n * 512];
        #pragma unroll
        for (int m = 0; m < 4; ++m)
            #pragma unroll
            for (int n = 0; n < 2; ++n)
                acc[m][n] = __builtin_amdgcn_mfma_f32_16x16x32_bf16(af[m], bfv[n], acc[m][n], 0, 0, 0);
    };

    const int nk = Sdim / 32;   // 16
    f32x4 P0, P1, Q0, Q1, R0, R1, N0, N1;
    auto loadA = [&](int kt, f32x4& v0, f32x4& v1) {
        const float* p = pA_f32 + kt * 32;
        v0 = *(const f32x4 GLOBAL_AS*)(p);
        v1 = *(const f32x4 GLOBAL_AS*)(p + 4);
    };
    auto writeA = [&](int buf, const f32x4& v0, const f32x4& v1) {
        s16x8 w;
        #pragma unroll
        for (int j = 0; j < 4; ++j) { w[j] = f2bf(v0[j]); w[4 + j] = f2bf(v1[j]); }
        *(s16x8*)&pool[buf * 4096 + aWr] = w;   // compiler auto-waits the loads
    };
    // prologue: buf0 written; A(1..3)+B(0..3) in flight
    loadA(0, P0, P1); stageB(0, 0);
    writeA(0, P0, P1);
    loadA(1, P0, P1); stageB(1, 1);
    loadA(2, Q0, Q1); stageB(2, 2);
    loadA(3, R0, R1); stageB(3, 3);
    int bc = 0, bw = 1, bs = 4;          // compute / writeA / stage buffer idx
    for (int kt = 0; kt < nk; ++kt) {
        const int rem = nk - 1 - kt;
        if (rem >= 3)      asm volatile("s_waitcnt vmcnt(9) lgkmcnt(0)" ::: "memory");
        else if (rem == 2) asm volatile("s_waitcnt vmcnt(6) lgkmcnt(0)" ::: "memory");
        else if (rem == 1) asm volatile("s_waitcnt vmcnt(3) lgkmcnt(0)" ::: "memory");
        else               asm volatile("s_waitcnt vmcnt(0) lgkmcnt(0)" ::: "memory");
        __builtin_amdgcn_s_barrier();
        __builtin_amdgcn_sched_barrier(0);
        if (kt + 4 < nk) { loadA(kt + 4, N0, N1); stageB(bs, kt + 4); }
        compute(bc);
        if (kt + 1 < nk) writeA(bw, P0, P1);
        P0 = Q0; P1 = Q1; Q0 = R0; Q1 = R1; R0 = N0; R1 = N1;
        bc = (bc == 4) ? 0 : bc + 1;
        bw = (bw == 4) ? 0 : bw + 1;
        bs = (bs == 4) ? 0 : bs + 1;
    }

    // ---- LDS-transpose epilogue -> contiguous yT stores
    __syncthreads();
    short* T = pool;
    #pragma unroll
    for (int i = 0; i < 4; ++i) {
        const int ml = wr * 64 + i * 16 + lkq * 4;
        #pragma unroll
        for (int j = 0; j < 2; ++j) {
            const int ql = wc * 32 + j * 16 + lr;
            s16x4 v;
            #pragma unroll
            for (int r = 0; r < 4; ++r) v[r] = f2bf(acc[i][j][r]);
            *(s16x4*)&T[ql * 132 + ml] = v;
        }
    }
    __syncthreads();
    short* Oy = yT;
    #pragma unroll
    for (int p = 0; p < 4; ++p) {
        const int ql = p * 32 + (t >> 4);
        const int gq = n0 + ql;
        const int mlc = (t & 15) * 8;
        const s16x8 v = *(const s16x8*)&T[ql * 132 + mlc];
        const int gm0 = m0 + mlc;
        if (gq < Cdim && gm0 < MF) {
            const int b0 = gm0 / Cdim;
            const int c0 = gm0 - b0 * Cdim;
            if (c0 + 8 <= Cdim) {
                *(s16x8*)&Oy[((long)b0 * Cdim + gq) * CpK + c0] = v;
            } else {
                #pragma unroll
                for (int r = 0; r < 8; ++r) {
                    const int gm = gm0 + r;
                    if (gm < MF) {
                        const int bb = gm / Cdim;
                        const int cc = gm - bb * Cdim;
                        Oy[((long)bb * Cdim + gq) * CpK + cc] = v[r];
                    }
                }
            }
        }
    }
}

// ---------------- gemm8: 128x128, 8 waves, 5 bufs depth-4, gload A+B -------
__global__ __launch_bounds__(512, 4) void gemm8k(
    const short* __restrict__ A,       // pwb [512][288]
    const short* __restrict__ BT,      // yT  [17408][288]
    float* __restrict__ O,             // out [64][512][271]
    const float* __restrict__ bias)
{
    const int m0 = blockIdx.y * 128;
    const int n0 = blockIdx.x * 128;
    __shared__ short pool[40960];      // A 5x4096 @0, B 5x4096 @20480. 80KB.

    const int t = threadIdx.x;
    const int lane = t & 63;
    const int wid = t >> 6;
    const int wr = wid >> 2;
    const int wc = wid & 3;
    const int lr = lane & 15, lkq = lane >> 4;

    f32x4 acc[4][2];
    #pragma unroll
    for (int i = 0; i < 4; ++i)
        #pragma unroll
        for (int j = 0; j < 2; ++j)
            acc[i][j] = (f32x4){0.f, 0.f, 0.f, 0.f};

    const int srow = wid * 16 + (lane >> 2);
    const int skk  = (((lane & 3) ^ ((lane >> 3) & 3)) * 8);
    const short* pA = A + (long)(m0 + srow) * CpK + skk;
    const short* pB = BT + (long)(n0 + srow) * CpK + skk;
    const int ldsOff = wid * 512;

    const int kxs = ((lkq ^ ((lr >> 1) & 3)) << 3);
    const int aBase = (wr * 64 + lr) * 32 + kxs;
    const int bBase = (wc * 32 + lr) * 32 + kxs;

    auto stage = [&](int buf, int kt) {
        __builtin_amdgcn_global_load_lds((const GLOBAL_AS void*)(pA + kt * 32),
            (LDS_AS void*)&pool[buf * 4096 + ldsOff], 16, 0, 0);
        __builtin_amdgcn_global_load_lds((const GLOBAL_AS void*)(pB + kt * 32),
            (LDS_AS void*)&pool[20480 + buf * 4096 + ldsOff], 16, 0, 0);
    };
    auto compute = [&](int buf) {
        s16x8 af[4], bfv[2];
        #pragma unroll
        for (int m = 0; m < 4; ++m)
            af[m] = *(const s16x8*)&pool[buf * 4096 + aBase + m * 512];
        #pragma unroll
        for (int n = 0; n < 2; ++n)
            bfv[n] = *(const s16x8*)&pool[20480 + buf * 4096 + bBase + n * 512];
        #pragma unroll
        for (int m = 0; m < 4; ++m)
            #pragma unroll
            for (int n = 0; n < 2; ++n)
                acc[m][n] = __builtin_amdgcn_mfma_f32_16x16x32_bf16(af[m], bfv[n], acc[m][n], 0, 0, 0);
    };

    const int nk = CpK / 32;   // 9
    stage(0, 0); stage(1, 1); stage(2, 2); stage(3, 3);
    int bc = 0, bs = 4;
    for (int kt = 0; kt < nk; ++kt) {
        const int rem = nk - 1 - kt;
        if (rem >= 3)      asm volatile("s_waitcnt vmcnt(6)" ::: "memory");
        else if (rem == 2) asm volatile("s_waitcnt vmcnt(4)" ::: "memory");
        else if (rem == 1) asm volatile("s_waitcnt vmcnt(2)" ::: "memory");
        else               asm volatile("s_waitcnt vmcnt(0)" ::: "memory");
        __builtin_amdgcn_s_barrier();
        __builtin_amdgcn_sched_barrier(0);
        if (kt + 4 < nk) stage(bs, kt + 4);
        compute(bc);
        bc = (bc == 4) ? 0 : bc + 1;
        bs = (bs == 4) ? 0 : bs + 1;
    }

    #pragma unroll
    for (int j = 0; j < 2; ++j) {
        const int gn = n0 + wc * 32 + j * 16 + lr;
        if (gn >= MF) continue;
        const int b = gn / Cdim;
        const int q = gn - b * Cdim;
        float* ob = O + (long)b * Odim * Cdim + q;
        #pragma unroll
        for (int i = 0; i < 4; ++i) {
            const int gmb = m0 + wr * 64 + i * 16 + lkq * 4;
            #pragma unroll
            for (int r = 0; r < 4; ++r) {
                const int gm = gmb + r;
                ob[(long)gm * Cdim] = acc[i][j][r] + bias[gm];
            }
        }
    }
}

// ---------------- ff separable reduction -> GT[128][512] ----------------
__global__ __launch_bounds__(256) void ff_reduce(const float* __restrict__ ff,
                                                 float* __restrict__ GT)
{
    __shared__ float L[2][32 * 132];
    const int t = threadIdx.x;
    const int half = t >> 7;
    const int tl = t & 127;
    const int o = blockIdx.x * 2 + half;
    const float* base = ff + (long)o * 4096;
    #pragma unroll
    for (int ch = 0; ch < 8; ++ch) {
        const int g = ch * 512 + tl * 4;
        const f32x4 v = *(const f32x4*)&base[g];
        *(f32x4*)&L[half][(g >> 7) * 132 + (g & 127)] = v;
    }
    __syncthreads();
    const int gq = tl >> 5, idx = tl & 31;
    float s = 0.f;
    if (gq == 0 || gq == 2) {
        const int w = (gq == 0) ? 0 : 2;
        #pragma unroll 8
        for (int j = 0; j < 32; ++j) s += L[half][idx * 132 + j * 4 + w];
    } else {
        const int w = (gq == 1) ? 1 : 3;
        #pragma unroll 8
        for (int i = 0; i < 32; ++i) s += L[half][i * 132 + idx * 4 + w];
    }
    GT[tl * 512 + o] = s;
}

__device__ __forceinline__ float wave_max(float v) {
    #pragma unroll
    for (int off = 32; off; off >>= 1) v = fmaxf(v, __shfl_xor(v, off));
    return v;
}
__device__ __forceinline__ float wave_sum(float v) {
    #pragma unroll
    for (int off = 32; off; off >>= 1) v += __shfl_xor(v, off);
    return v;
}

// ---- att4: 4 columns per block. Blocks 68..103 build pwb instead.
__global__ __launch_bounds__(512) void att4(
    const float* __restrict__ GT,   // [128][512]
    const float* __restrict__ sp,   // [271][2]
    short* __restrict__ attT,       // [384][512]
    const float* __restrict__ pw,   // [512][271]
    short* __restrict__ pwb)        // [512][288]
{
    const int blk = blockIdx.x;
    const int t = threadIdx.x;      // 0..511
    if (blk >= 68) {
        const int bi = blk - 68;
        const int idx8 = (bi * 512 + t) * 8;
        const int p = idx8 / CpK;
        const int k0 = idx8 - p * CpK;
        s16x8 v;
        #pragma unroll
        for (int r = 0; r < 8; ++r) {
            const int k = k0 + r;
            v[r] = (k < Cdim) ? f2bf(pw[(long)p * Cdim + k]) : (short)0;
        }
        *(s16x8*)&pwb[idx8] = v;
        return;
    }

    const int c0 = blk * 4;
    __shared__ float u[4][128];
    __shared__ float red[32];
    {
        const int ci = t >> 7, k = t & 127;
        const int csafe = (c0 + ci < Cdim) ? (c0 + ci) : (Cdim - 1);
        const int g = k >> 5, kk = k & 31;
        const float f = 6.283185307179586477f * (float)kk / 32.0f;
        const float p = sp[csafe * 2 + (g & 1)];
        const float ang = p * f;
        u[ci][k] = (g < 2) ? sinf(ang) : cosf(ang);
    }
    __syncthreads();

    float l[4] = {0.f, 0.f, 0.f, 0.f};
    #pragma unroll 8
    for (int k = 0; k < 128; ++k) {
        const float g = GT[k * 512 + t];
        #pragma unroll
        for (int ci = 0; ci < 4; ++ci) l[ci] = fmaf(g, u[ci][k], l[ci]);
    }

    const int lane = t & 63, wid = t >> 6;
    float m[4];
    #pragma unroll
    for (int ci = 0; ci < 4; ++ci) m[ci] = wave_max(l[ci]);
    if (lane == 0) {
        #pragma unroll
        for (int ci = 0; ci < 4; ++ci) red[wid * 4 + ci] = m[ci];
    }
    __syncthreads();
    #pragma unroll
    for (int ci = 0; ci < 4; ++ci) {
        float mm = red[ci];
        #pragma unroll
        for (int w = 1; w < 8; ++w) mm = fmaxf(mm, red[w * 4 + ci]);
        m[ci] = mm;
    }
    __syncthreads();
    float e[4], s[4];
    #pragma unroll
    for (int ci = 0; ci < 4; ++ci) { e[ci] = expf(l[ci] - m[ci]); s[ci] = wave_sum(e[ci]); }
    if (lane == 0) {
        #pragma unroll
        for (int ci = 0; ci < 4; ++ci) red[wid * 4 + ci] = s[ci];
    }
    __syncthreads();
    #pragma unroll
    for (int ci = 0; ci < 4; ++ci) {
        float ss = red[ci];
        #pragma unroll
        for (int w = 1; w < 8; ++w) ss += red[w * 4 + ci];
        const int c = c0 + ci;
        if (c < Cdim) attT[(long)c * Sdim + t] = f2bf(e[ci] / ss);
    }
}

extern "C" void kernel_launch(void* const* d_in, const int* in_sizes, int n_in,
                              void* d_out, int out_size, void* d_ws, size_t ws_size,
                              hipStream_t stream)
{
    const float* x  = (const float*)d_in[0];  // [B,C,S] = [17344][512]
    const float* ff = (const float*)d_in[1];  // [512,32,32,4]
    const float* sp = (const float*)d_in[2];  // [271,2]
    const float* pw = (const float*)d_in[3];  // [512,271]
    const float* pb = (const float*)d_in[4];  // [512]
    float* out = (float*)d_out;               // [64,512,271]

    float* ws   = (float*)d_ws;
    float* GT   = ws;                           // 128*512 f32
    short* attT = (short*)(GT + 128 * 512);     // 384*512 bf16
    short* pwb  = attT + 384L * Sdim;           // 512*288 bf16
    short* yT   = pwb + (long)Odim * CpK;       // 17408*288 bf16

    ff_reduce<<<256, 256, 0, stream>>>(ff, GT);
    att4<<<104, 512, 0, stream>>>(GT, sp, attT, pw, pwb);

    // gemm7: yT[(b*271+q)][c] = sum_s x[(b,c)][s] * attT[q][s]
    // grid row-fastest: 3 sharers of each A-row-tile spaced 136 = 0 mod 8.
    gemm7<<<dim3(MFp / 128, 3), 512, 0, stream>>>(x, attT, yT);

    // gemm8: out[b,p,q] = sum_k pwb[p][k] * yT[(b*271+q)][k] + pb[p]
    gemm8k<<<dim3(MFp / 128, Odim / 128), 512, 0, stream>>>(pwb, yT, out, pb);
}

// Round 19
// 56.815 us; speedup vs baseline: 1.0144x; 1.0144x over previous
//
#include <hip/hip_runtime.h>
#include <hip/hip_bf16.h>
#include <math.h>

// B=64, C=271, S=512, O=512, K=32.
// out[b,p,q] = sum_c pw[p,c]*y[b,c,q] + pb[p],  y[b,c,q] = sum_s x[b,c,s]*att[s,q]
// att = softmax_o( GT[128,o] . u[c,128] )  (separable fourier reduction)
// FINAL (R15 config, best measured 56.8us): both GEMMs 4 LDS buffers /
// 3 tiles in flight (T4 counted vmcnt, drain 4->2->0), 8 waves, 128x128.
// gemm7 A-regs rotate P<-Q<-N (depth 3). 64KB pools -> 2 blocks/CU.

typedef short s16x8 __attribute__((ext_vector_type(8)));
typedef short s16x4 __attribute__((ext_vector_type(4)));
typedef float f32x4 __attribute__((ext_vector_type(4)));

#define GLOBAL_AS __attribute__((address_space(1)))
#define LDS_AS    __attribute__((address_space(3)))

__device__ __forceinline__ short f2bf(float f) {
    __hip_bfloat16 h = __float2bfloat16(f);
    return *reinterpret_cast<short*>(&h);
}

#define Cdim 271
#define CpK  288
#define Sdim 512
#define Odim 512
#define MF   17344
#define MFp  17408

// ---------------- gemm7: 128x128, 8 waves, 4 bufs depth-3, f32 A ----------
__global__ __launch_bounds__(512, 4) void gemm7(
    const float* __restrict__ x,
    const short* __restrict__ BT,
    short* __restrict__ yT)
{
    const int m0 = blockIdx.x * 128;     // row tile (x rows)
    const int n0 = blockIdx.y * 128;     // q tile
    // A bufs 4 x 4096 shorts @0; B bufs 4 x 4096 @16384. 64KB.
    // Epilogue reuses pool[0..16896) as T[128][132].
    __shared__ short pool[32768];

    const int t = threadIdx.x;
    const int lane = t & 63;
    const int wid = t >> 6;
    const int wr = wid >> 2;
    const int wc = wid & 3;
    const int lr = lane & 15, lkq = lane >> 4;

    f32x4 acc[4][2];
    #pragma unroll
    for (int i = 0; i < 4; ++i)
        #pragma unroll
        for (int j = 0; j < 2; ++j)
            acc[i][j] = (f32x4){0.f, 0.f, 0.f, 0.f};

    const int srowB = wid * 16 + (lane >> 2);
    const int skk   = (((lane & 3) ^ ((lane >> 3) & 3)) * 8);
    const short* pB = BT + (long)(n0 + srowB) * Sdim + skk;
    const int ldsOff = wid * 512;

    const int arow = t >> 2;
    const int aslot = t & 3;
    const int afc = (aslot ^ ((arow >> 1) & 3)) * 8;
    const int agrow = (m0 + arow < MF) ? (m0 + arow) : (MF - 1);
    const float* pA_f32 = x + (long)agrow * Sdim + afc;
    const int aWr = arow * 32 + aslot * 8;

    const int kxs = ((lkq ^ ((lr >> 1) & 3)) << 3);
    const int aBase = (wr * 64 + lr) * 32 + kxs;
    const int bBase = (wc * 32 + lr) * 32 + kxs;

    auto stageB = [&](int buf, int kt) {
        __builtin_amdgcn_global_load_lds((const GLOBAL_AS void*)(pB + kt * 32),
            (LDS_AS void*)&pool[16384 + buf * 4096 + ldsOff], 16, 0, 0);
    };
    auto compute = [&](int buf) {
        s16x8 af[4], bfv[2];
        #pragma unroll
        for (int m = 0; m < 4; ++m)
            af[m] = *(const s16x8*)&pool[buf * 4096 + aBase + m * 512];
        #pragma unroll
        for (int n = 0; n < 2; ++n)
            bfv[n] = *(const s16x8*)&pool[16384 + buf * 4096 + bBase + n * 512];
        #pragma unroll
        for (int m = 0; m < 4; ++m)
            #pragma unroll
            for (int n = 0; n < 2; ++n)
                acc[m][n] = __builtin_amdgcn_mfma_f32_16x16x32_bf16(af[m], bfv[n], acc[m][n], 0, 0, 0);
    };

    const int nk = Sdim / 32;   // 16
    f32x4 P0, P1, Q0, Q1, N0, N1;
    auto loadA = [&](int kt, f32x4& v0, f32x4& v1) {
        const float* p = pA_f32 + kt * 32;
        v0 = *(const f32x4 GLOBAL_AS*)(p);
        v1 = *(const f32x4 GLOBAL_AS*)(p + 4);
    };
    auto writeA = [&](int buf, const f32x4& v0, const f32x4& v1) {
        s16x8 w;
        #pragma unroll
        for (int j = 0; j < 4; ++j) { w[j] = f2bf(v0[j]); w[4 + j] = f2bf(v1[j]); }
        *(s16x8*)&pool[buf * 4096 + aWr] = w;   // compiler auto-waits the loads
    };
    // prologue: buf0 written; A(1),A(2) + B(0..2) in flight
    loadA(0, P0, P1); stageB(0, 0);
    writeA(0, P0, P1);
    loadA(1, P0, P1); stageB(1, 1);
    loadA(2, Q0, Q1); stageB(2, 2);
    for (int kt = 0; kt < nk; ++kt) {
        const int rem = nk - 1 - kt;
        if (rem >= 2)      asm volatile("s_waitcnt vmcnt(4) lgkmcnt(0)" ::: "memory");
        else if (rem == 1) asm volatile("s_waitcnt vmcnt(2) lgkmcnt(0)" ::: "memory");
        else               asm volatile("s_waitcnt vmcnt(0) lgkmcnt(0)" ::: "memory");
        __builtin_amdgcn_s_barrier();
        __builtin_amdgcn_sched_barrier(0);
        if (kt + 3 < nk) { loadA(kt + 3, N0, N1); stageB((kt + 3) & 3, kt + 3); }
        compute(kt & 3);
        if (kt + 1 < nk) writeA((kt + 1) & 3, P0, P1);
        P0 = Q0; P1 = Q1; Q0 = N0; Q1 = N1;
    }

    // ---- LDS-transpose epilogue -> contiguous yT stores
    __syncthreads();
    short* T = pool;
    #pragma unroll
    for (int i = 0; i < 4; ++i) {
        const int ml = wr * 64 + i * 16 + lkq * 4;
        #pragma unroll
        for (int j = 0; j < 2; ++j) {
            const int ql = wc * 32 + j * 16 + lr;
            s16x4 v;
            #pragma unroll
            for (int r = 0; r < 4; ++r) v[r] = f2bf(acc[i][j][r]);
            *(s16x4*)&T[ql * 132 + ml] = v;
        }
    }
    __syncthreads();
    short* Oy = yT;
    #pragma unroll
    for (int p = 0; p < 4; ++p) {
        const int ql = p * 32 + (t >> 4);
        const int gq = n0 + ql;
        const int mlc = (t & 15) * 8;
        const s16x8 v = *(const s16x8*)&T[ql * 132 + mlc];
        const int gm0 = m0 + mlc;
        if (gq < Cdim && gm0 < MF) {
            const int b0 = gm0 / Cdim;
            const int c0 = gm0 - b0 * Cdim;
            if (c0 + 8 <= Cdim) {
                *(s16x8*)&Oy[((long)b0 * Cdim + gq) * CpK + c0] = v;
            } else {
                #pragma unroll
                for (int r = 0; r < 8; ++r) {
                    const int gm = gm0 + r;
                    if (gm < MF) {
                        const int bb = gm / Cdim;
                        const int cc = gm - bb * Cdim;
                        Oy[((long)bb * Cdim + gq) * CpK + cc] = v[r];
                    }
                }
            }
        }
    }
}

// ---------------- gemm8: 128x128, 8 waves, 4 bufs depth-3, gload A+B -------
__global__ __launch_bounds__(512, 4) void gemm8k(
    const short* __restrict__ A,       // pwb [512][288]
    const short* __restrict__ BT,      // yT  [17408][288]
    float* __restrict__ O,             // out [64][512][271]
    const float* __restrict__ bias)
{
    const int m0 = blockIdx.y * 128;
    const int n0 = blockIdx.x * 128;
    __shared__ short pool[32768];      // A 4x4096 @0, B 4x4096 @16384. 64KB.

    const int t = threadIdx.x;
    const int lane = t & 63;
    const int wid = t >> 6;
    const int wr = wid >> 2;
    const int wc = wid & 3;
    const int lr = lane & 15, lkq = lane >> 4;

    f32x4 acc[4][2];
    #pragma unroll
    for (int i = 0; i < 4; ++i)
        #pragma unroll
        for (int j = 0; j < 2; ++j)
            acc[i][j] = (f32x4){0.f, 0.f, 0.f, 0.f};

    const int srow = wid * 16 + (lane >> 2);
    const int skk  = (((lane & 3) ^ ((lane >> 3) & 3)) * 8);
    const short* pA = A + (long)(m0 + srow) * CpK + skk;
    const short* pB = BT + (long)(n0 + srow) * CpK + skk;
    const int ldsOff = wid * 512;

    const int kxs = ((lkq ^ ((lr >> 1) & 3)) << 3);
    const int aBase = (wr * 64 + lr) * 32 + kxs;
    const int bBase = (wc * 32 + lr) * 32 + kxs;

    auto stage = [&](int buf, int kt) {
        __builtin_amdgcn_global_load_lds((const GLOBAL_AS void*)(pA + kt * 32),
            (LDS_AS void*)&pool[buf * 4096 + ldsOff], 16, 0, 0);
        __builtin_amdgcn_global_load_lds((const GLOBAL_AS void*)(pB + kt * 32),
            (LDS_AS void*)&pool[16384 + buf * 4096 + ldsOff], 16, 0, 0);
    };
    auto compute = [&](int buf) {
        s16x8 af[4], bfv[2];
        #pragma unroll
        for (int m = 0; m < 4; ++m)
            af[m] = *(const s16x8*)&pool[buf * 4096 + aBase + m * 512];
        #pragma unroll
        for (int n = 0; n < 2; ++n)
            bfv[n] = *(const s16x8*)&pool[16384 + buf * 4096 + bBase + n * 512];
        #pragma unroll
        for (int m = 0; m < 4; ++m)
            #pragma unroll
            for (int n = 0; n < 2; ++n)
                acc[m][n] = __builtin_amdgcn_mfma_f32_16x16x32_bf16(af[m], bfv[n], acc[m][n], 0, 0, 0);
    };

    const int nk = CpK / 32;   // 9
    stage(0, 0); stage(1, 1); stage(2, 2);
    for (int kt = 0; kt < nk; ++kt) {
        const int rem = nk - 1 - kt;
        if (rem >= 2)      asm volatile("s_waitcnt vmcnt(4)" ::: "memory");
        else if (rem == 1) asm volatile("s_waitcnt vmcnt(2)" ::: "memory");
        else               asm volatile("s_waitcnt vmcnt(0)" ::: "memory");
        __builtin_amdgcn_s_barrier();
        __builtin_amdgcn_sched_barrier(0);
        if (kt + 3 < nk) stage((kt + 3) & 3, kt + 3);
        compute(kt & 3);
    }

    #pragma unroll
    for (int j = 0; j < 2; ++j) {
        const int gn = n0 + wc * 32 + j * 16 + lr;
        if (gn >= MF) continue;
        const int b = gn / Cdim;
        const int q = gn - b * Cdim;
        float* ob = O + (long)b * Odim * Cdim + q;
        #pragma unroll
        for (int i = 0; i < 4; ++i) {
            const int gmb = m0 + wr * 64 + i * 16 + lkq * 4;
            #pragma unroll
            for (int r = 0; r < 4; ++r) {
                const int gm = gmb + r;
                ob[(long)gm * Cdim] = acc[i][j][r] + bias[gm];
            }
        }
    }
}

// ---------------- ff separable reduction -> GT[128][512] ----------------
__global__ __launch_bounds__(256) void ff_reduce(const float* __restrict__ ff,
                                                 float* __restrict__ GT)
{
    __shared__ float L[2][32 * 132];
    const int t = threadIdx.x;
    const int half = t >> 7;
    const int tl = t & 127;
    const int o = blockIdx.x * 2 + half;
    const float* base = ff + (long)o * 4096;
    #pragma unroll
    for (int ch = 0; ch < 8; ++ch) {
        const int g = ch * 512 + tl * 4;
        const f32x4 v = *(const f32x4*)&base[g];
        *(f32x4*)&L[half][(g >> 7) * 132 + (g & 127)] = v;
    }
    __syncthreads();
    const int gq = tl >> 5, idx = tl & 31;
    float s = 0.f;
    if (gq == 0 || gq == 2) {
        const int w = (gq == 0) ? 0 : 2;
        #pragma unroll 8
        for (int j = 0; j < 32; ++j) s += L[half][idx * 132 + j * 4 + w];
    } else {
        const int w = (gq == 1) ? 1 : 3;
        #pragma unroll 8
        for (int i = 0; i < 32; ++i) s += L[half][i * 132 + idx * 4 + w];
    }
    GT[tl * 512 + o] = s;
}

__device__ __forceinline__ float wave_max(float v) {
    #pragma unroll
    for (int off = 32; off; off >>= 1) v = fmaxf(v, __shfl_xor(v, off));
    return v;
}
__device__ __forceinline__ float wave_sum(float v) {
    #pragma unroll
    for (int off = 32; off; off >>= 1) v += __shfl_xor(v, off);
    return v;
}

// ---- att4: 4 columns per block. Blocks 68..103 build pwb instead.
__global__ __launch_bounds__(512) void att4(
    const float* __restrict__ GT,   // [128][512]
    const float* __restrict__ sp,   // [271][2]
    short* __restrict__ attT,       // [384][512]
    const float* __restrict__ pw,   // [512][271]
    short* __restrict__ pwb)        // [512][288]
{
    const int blk = blockIdx.x;
    const int t = threadIdx.x;      // 0..511
    if (blk >= 68) {
        const int bi = blk - 68;
        const int idx8 = (bi * 512 + t) * 8;
        const int p = idx8 / CpK;
        const int k0 = idx8 - p * CpK;
        s16x8 v;
        #pragma unroll
        for (int r = 0; r < 8; ++r) {
            const int k = k0 + r;
            v[r] = (k < Cdim) ? f2bf(pw[(long)p * Cdim + k]) : (short)0;
        }
        *(s16x8*)&pwb[idx8] = v;
        return;
    }

    const int c0 = blk * 4;
    __shared__ float u[4][128];
    __shared__ float red[32];
    {
        const int ci = t >> 7, k = t & 127;
        const int csafe = (c0 + ci < Cdim) ? (c0 + ci) : (Cdim - 1);
        const int g = k >> 5, kk = k & 31;
        const float f = 6.283185307179586477f * (float)kk / 32.0f;
        const float p = sp[csafe * 2 + (g & 1)];
        const float ang = p * f;
        u[ci][k] = (g < 2) ? sinf(ang) : cosf(ang);
    }
    __syncthreads();

    float l[4] = {0.f, 0.f, 0.f, 0.f};
    #pragma unroll 8
    for (int k = 0; k < 128; ++k) {
        const float g = GT[k * 512 + t];
        #pragma unroll
        for (int ci = 0; ci < 4; ++ci) l[ci] = fmaf(g, u[ci][k], l[ci]);
    }

    const int lane = t & 63, wid = t >> 6;
    float m[4];
    #pragma unroll
    for (int ci = 0; ci < 4; ++ci) m[ci] = wave_max(l[ci]);
    if (lane == 0) {
        #pragma unroll
        for (int ci = 0; ci < 4; ++ci) red[wid * 4 + ci] = m[ci];
    }
    __syncthreads();
    #pragma unroll
    for (int ci = 0; ci < 4; ++ci) {
        float mm = red[ci];
        #pragma unroll
        for (int w = 1; w < 8; ++w) mm = fmaxf(mm, red[w * 4 + ci]);
        m[ci] = mm;
    }
    __syncthreads();
    float e[4], s[4];
    #pragma unroll
    for (int ci = 0; ci < 4; ++ci) { e[ci] = expf(l[ci] - m[ci]); s[ci] = wave_sum(e[ci]); }
    if (lane == 0) {
        #pragma unroll
        for (int ci = 0; ci < 4; ++ci) red[wid * 4 + ci] = s[ci];
    }
    __syncthreads();
    #pragma unroll
    for (int ci = 0; ci < 4; ++ci) {
        float ss = red[ci];
        #pragma unroll
        for (int w = 1; w < 8; ++w) ss += red[w * 4 + ci];
        const int c = c0 + ci;
        if (c < Cdim) attT[(long)c * Sdim + t] = f2bf(e[ci] / ss);
    }
}

extern "C" void kernel_launch(void* const* d_in, const int* in_sizes, int n_in,
                              void* d_out, int out_size, void* d_ws, size_t ws_size,
                              hipStream_t stream)
{
    const float* x  = (const float*)d_in[0];  // [B,C,S] = [17344][512]
    const float* ff = (const float*)d_in[1];  // [512,32,32,4]
    const float* sp = (const float*)d_in[2];  // [271,2]
    const float* pw = (const float*)d_in[3];  // [512,271]
    const float* pb = (const float*)d_in[4];  // [512]
    float* out = (float*)d_out;               // [64,512,271]

    float* ws   = (float*)d_ws;
    float* GT   = ws;                           // 128*512 f32
    short* attT = (short*)(GT + 128 * 512);     // 384*512 bf16
    short* pwb  = attT + 384L * Sdim;           // 512*288 bf16
    short* yT   = pwb + (long)Odim * CpK;       // 17408*288 bf16

    ff_reduce<<<256, 256, 0, stream>>>(ff, GT);
    att4<<<104, 512, 0, stream>>>(GT, sp, attT, pw, pwb);

    // gemm7: yT[(b*271+q)][c] = sum_s x[(b,c)][s] * attT[q][s]
    // grid row-fastest: 3 sharers of each A-row-tile spaced 136 = 0 mod 8.
    gemm7<<<dim3(MFp / 128, 3), 512, 0, stream>>>(x, attT, yT);

    // gemm8: out[b,p,q] = sum_k pwb[p][k] * yT[(b*271+q)][k] + pb[p]
    gemm8k<<<dim3(MFp / 128, Odim / 128), 512, 0, stream>>>(pwb, yT, out, pb);
}